// Round 6
// baseline (115.714 us; speedup 1.0000x reference)
//
#include <hip/hip_runtime.h>

#define NPTS 16384
#define TH 33.33f

typedef __attribute__((ext_vector_type(8)))  __bf16 bf16x8;
typedef __attribute__((ext_vector_type(16))) float  f32x16;
typedef __attribute__((ext_vector_type(16))) unsigned u32x16;

__device__ __forceinline__ unsigned short f2bf(float x) {
    unsigned u = __float_as_uint(x);
    u += 0x7FFFu + ((u >> 16) & 1u);
    return (unsigned short)(u >> 16);
}
__device__ __forceinline__ float bf2f(unsigned short h) {
    return __uint_as_float(((unsigned)h) << 16);
}
__device__ __forceinline__ unsigned umin_(unsigned a, unsigned b) { return a < b ? a : b; }

union UV { uint4 v; bf16x8 h; unsigned short s[8]; };

// ws: pfmt byte[4 set][16384 pt][32] (4 MB) + d2part float[4 db][128 rb][8 seg][128] (2 MB).
// fragment map: elem = (g*32 + idx)*8 + j with k = g*8 + j (verified R2-R16)
// A k: [qh(3), ql(3), qh(2) | zh, 1,1,1, 1.0, 0,0,0]
// B k: [ph(3), ph(3), pl(2) | zl, -hp0,-hp1,-hp2, -32, 0,0,0]
// score s'' = q.p - hp - 32 (strictly negative) ; d^2 = 2*(hq - 32 - s'')
// Fold: negative floats => float-max == uint-min on bits; umin3 chains (R18).
//
// === DIAGNOSIS LEDGER ===
// R21 ((256,8) + prep + 1-tile/wave) = MIXED: Occupancy 30->60 (TLP step REAL), but
//   (a) staging copy lw[tid*4+s] => lanes at stride 64B => 8-way bank conflict,
//       SQ_LDS_BANK_CONFLICT 0 -> 6.29M (~10 us serialization); R11 violated by INDEXING.
//   (b) dropped R9 hoist: chunk c+1 global load issued after barrier => full latency
//       exposed to all waves of the block.
// R22 (this): same structure; copy index {tid, 256+tid, 512+tid, 768+tid} (identity
//   image, lane-consecutive-16B, coalesced 4KB/wave) + hoisted staging regs (R9 form,
//   +16 VGPR => ~48 <= 64-reg occupancy step).
// R20: occupancy quantum is POWER-OF-2 (<=64 regs -> 8 w/SIMD, <=128 -> 4; no 5/6/7).
// R19: +32 live VGPR at 128-cap => spill. R17: in-loop col-fold = +25 us. R18: neutral.
// Per-MFMA cost (m119): 32x32x16 bf16 ~= 32 cyc/SIMD. Matrix demand 16.5k cyc/SIMD/round.
//
// === FROZEN LEDGER (R2-R16) ===
// R11: every ds_write must be lane-consecutive-16B. R5/R7: no inline asm on MFMA results.
// R15/R16: unroll-2 / shuffle-epilogue = +14us (AGPR<->VGPR copy tax). Keep unroll 1
//   + LDS-scratch epilogue.
// TIMING: dur_us includes fixed ~48us harness re-poison fill (268 MB). Addressable
//   budget = prep (~0.5) + chamfer + merge (~1.3).

// ---- prep: convert all points of both tensors/batches to the 32B LDS-image format ----
// set: 0,1 = src[b] ; 2,3 = tgt[b].  point p -> offset (p>>5)*1024 + (p&31)*16 (+512 for c1)
__global__ __launch_bounds__(256) void prep_kernel(
        const float* __restrict__ src, const float* __restrict__ tgt,
        unsigned char* __restrict__ pfmt, float* __restrict__ out)
{
    const int set = blockIdx.y;                   // 4 sets
    const int chunk = blockIdx.x;                 // 64 chunks x 256 pts
    const int tid = threadIdx.x;
    if (set == 0 && chunk == 0 && tid < 2) out[tid] = 0.0f;   // replaces memset node
    const float* base = (set < 2 ? src : tgt) + (size_t)(set & 1) * NPTS * 3;
    const int p = chunk * 256 + tid;
    const float x = base[p * 3 + 0], y = base[p * 3 + 1], z = base[p * 3 + 2];

    float hp = 0.5f * fmaf(z, z, fmaf(y, y, x * x));
    unsigned short xh = f2bf(x), yh = f2bf(y), zh = f2bf(z);
    unsigned short xl = f2bf(x - bf2f(xh)), yl = f2bf(y - bf2f(yh)), zl = f2bf(z - bf2f(zh));
    float rr = hp;
    unsigned short h0 = f2bf(rr); rr -= bf2f(h0);
    unsigned short h1 = f2bf(rr); rr -= bf2f(h1);
    unsigned short h2 = f2bf(rr);
    UV c0, c1;
    c0.s[0]=xh; c0.s[1]=yh; c0.s[2]=zh; c0.s[3]=xh; c0.s[4]=yh; c0.s[5]=zh; c0.s[6]=xl; c0.s[7]=yl;
    c1.s[0]=zl; c1.s[1]=(unsigned short)(h0^0x8000); c1.s[2]=(unsigned short)(h1^0x8000);
    c1.s[3]=(unsigned short)(h2^0x8000);
    c1.s[4]=0xC200;                     // bf16(-32) bias, pairs with A k12 = 1.0
    c1.s[5]=0; c1.s[6]=0; c1.s[7]=0;

    unsigned char* ob = pfmt + (size_t)set * NPTS * 32
                             + (size_t)(p >> 5) * 1024 + (size_t)(p & 31) * 16;
    *(uint4*)(ob)       = c0.v;
    *(uint4*)(ob + 512) = c1.v;
}

__global__ __launch_bounds__(256, 8) void chamfer_kernel(
        const float* __restrict__ src, const float* __restrict__ tgt,
        const unsigned char* __restrict__ pfmt, float* __restrict__ d2part)
{
    const int db = blockIdx.y, dir = db >> 1, b = db & 1;
    const int rowblock = blockIdx.x >> 3, seg = blockIdx.x & 7;   // 128 rowblocks x 8 segs
    const int tid = threadIdx.x, wave = tid >> 6, lane = tid & 63;
    const int g = lane >> 5, cc = lane & 31;
    const float* qp = (dir == 0 ? src : tgt) + (size_t)b * NPTS * 3;
    const int pset = (dir == 0 ? 2 + b : b);
    const unsigned char* ps = pfmt + (size_t)pset * NPTS * 32 + (size_t)seg * 2048 * 32;
    const unsigned short one = 0x3F80;

    // 16 KB stage buffer; aliased as 16.9 KB epilogue scratch (4 waves * 1056 words)
    __shared__ alignas(16) unsigned char smem[16896];
    unsigned* scratch = (unsigned*)smem;

    // ---- A fragment + hq: ONE 32-row tile per wave (acc 16 regs) ----
    const int rt = rowblock * 4 + wave;
    bf16x8 afrag; float hq;
    {
        int r = rt * 32 + cc;
        float x = qp[r * 3 + 0], y = qp[r * 3 + 1], z = qp[r * 3 + 2];
        hq = 0.5f * fmaf(z, z, fmaf(y, y, x * x));
        unsigned short xh = f2bf(x), yh = f2bf(y), zh = f2bf(z);
        unsigned short xl = f2bf(x - bf2f(xh)), yl = f2bf(y - bf2f(yh)), zl = f2bf(z - bf2f(zh));
        UV f0, f1, rv;
        f0.s[0]=xh; f0.s[1]=yh; f0.s[2]=zh; f0.s[3]=xl; f0.s[4]=yl; f0.s[5]=zl; f0.s[6]=xh; f0.s[7]=yh;
        f1.s[0]=zh; f1.s[1]=one; f1.s[2]=one; f1.s[3]=one;
        f1.s[4]=one;                    // k12: pairs with B's bf16(-32) bias slot
        f1.s[5]=0; f1.s[6]=0; f1.s[7]=0;
        rv.v = g ? f1.v : f0.v;
        afrag = rv.h;
    }

    u32x16 m0 = 0xFF800000u;            // bits of -inf: umin identity here
    const f32x16 zc = 0.0f;

    // R22 staging: identity copy, index {tid, 256+tid, 512+tid, 768+tid}:
    // every ds_write_b128 lane-consecutive-16B (R11, 0 conflicts); every global
    // load a coalesced 4KB wave segment. Regs held across pt loop (R9 hoist).
    uint4 s0, s1, s2, s3;
#define STAGE_LOAD(CC) { \
    const uint4* gsrc = (const uint4*)(ps + (size_t)(CC) * 16384); \
    s0 = gsrc[tid]; s1 = gsrc[256 + tid]; s2 = gsrc[512 + tid]; s3 = gsrc[768 + tid]; }
#define STAGE_WRITE { \
    uint4* lw = (uint4*)smem; \
    lw[tid] = s0; lw[256 + tid] = s1; lw[512 + tid] = s2; lw[768 + tid] = s3; }

    STAGE_LOAD(0)
    STAGE_WRITE
    __syncthreads();
#pragma unroll 1
    for (int c = 0; c < 4; ++c) {                 // 4 chunks x 16 col-tiles
        if (c < 3) STAGE_LOAD(c + 1)              // issue loads; latency under pt loop
        const unsigned short* bb = (const unsigned short*)smem;
#pragma unroll 1
        for (int pt = 0; pt < 8; ++pt) {          // 2 col-tiles per iter
            bf16x8 q0 = *(const bf16x8*)(bb + pt * 1024 + lane * 8);
            bf16x8 q1 = *(const bf16x8*)(bb + pt * 1024 + 512 + lane * 8);
            f32x16 t0 = __builtin_amdgcn_mfma_f32_32x32x16_bf16(afrag, q0, zc, 0, 0, 0);
            f32x16 t1 = __builtin_amdgcn_mfma_f32_32x32x16_bf16(afrag, q1, zc, 0, 0, 0);
#pragma unroll
            for (int j = 0; j < 16; j++)
                m0[j] = umin_(umin_(__float_as_uint(t0[j]), __float_as_uint(t1[j])), m0[j]);
        }
        __syncthreads();                          // all waves done reading buffer
        if (c < 3) {
            STAGE_WRITE
            __syncthreads();                      // staged data visible to all waves
        }
    }

    // ---- epilogue: acc bits -> padded LDS (per-wave private region) -> row reduce ----
    float* dst = d2part + (((size_t)(db * 128 + rowblock)) * 8 + seg) * 128;
    {
        unsigned* sc = scratch + wave * 1056;
#pragma unroll
        for (int j = 0; j < 16; j++) {
            int r0 = (j & 3) + 8 * (j >> 2) + 4 * g;
            sc[r0 * 33 + cc] = m0[j];
        }
        const unsigned* sr = sc + cc * 33 + g * 16;   // intra-wave dep: lgkmcnt orders it
        unsigned mx = 0xFF800000u;
#pragma unroll
        for (int k = 0; k < 16; k++) mx = umin_(mx, sr[k]);
        mx = umin_(mx, (unsigned)__shfl_xor((int)mx, 32, 64));
        if (lane < 32) {
            float sbi = __uint_as_float(mx);
            float d2 = 2.0f * (hq - 32.0f - sbi);
            float d = fminf(sqrtf(fmaxf(d2, 0.0f)), TH);
            dst[wave * 32 + lane] = d;
        }
    }
}

__global__ __launch_bounds__(256) void merge_kernel(const float* __restrict__ d2part,
                                                    float* __restrict__ out) {
    const int b = blockIdx.y;                     // batch
    const int slice = blockIdx.x;                 // 16 slices of 1024 rows
    const int tid = threadIdx.x;
    float s = 0.0f;
#pragma unroll
    for (int pass = 0; pass < 2; pass++) {        // dir 0 and dir 1
        const float* base = d2part + (size_t)(pass * 2 + b) * 128 * 8 * 128;
#pragma unroll
        for (int i = 0; i < 4; i++) {
            int r = slice * 1024 + i * 256 + tid;
            const float* p = base + (size_t)(r >> 7) * 1024 + (r & 127);
            float m = p[0];
#pragma unroll
            for (int sgi = 1; sgi < 8; sgi++) m = fminf(m, p[sgi * 128]);
            s += m;
        }
    }
#pragma unroll
    for (int off = 32; off > 0; off >>= 1) s += __shfl_down(s, off, 64);
    __shared__ float w[4];
    if ((tid & 63) == 0) w[tid >> 6] = s;
    __syncthreads();
    if (tid == 0) {
        float t = (w[0] + w[1]) + (w[2] + w[3]);
        atomicAdd(&out[b], t * (1.0f / (2.0f * NPTS)));  // (mean_fwd + mean_bwd) / 2
    }
}

extern "C" void kernel_launch(void* const* d_in, const int* in_sizes, int n_in,
                              void* d_out, int out_size, void* d_ws, size_t ws_size,
                              hipStream_t stream) {
    const float* src = (const float*)d_in[0];
    const float* tgt = (const float*)d_in[1];
    float* out = (float*)d_out;
    unsigned char* pfmt = (unsigned char*)d_ws;               // 4 MB
    float* d2part = (float*)(pfmt + (size_t)4 * 1024 * 1024); // 2 MB

    prep_kernel<<<dim3(64, 4), 256, 0, stream>>>(src, tgt, pfmt, out);
    chamfer_kernel<<<dim3(1024, 4), 256, 0, stream>>>(src, tgt, pfmt, d2part);
    merge_kernel<<<dim3(16, 2), 256, 0, stream>>>(d2part, out);
}

// Round 7
// 93.489 us; speedup vs baseline: 1.2377x; 1.2377x over previous
//
#include <hip/hip_runtime.h>

#define NPTS 16384
#define TH 33.33f

typedef __attribute__((ext_vector_type(8)))  __bf16 bf16x8;
typedef __attribute__((ext_vector_type(16))) float  f32x16;
typedef __attribute__((ext_vector_type(16))) unsigned u32x16;

__device__ __forceinline__ unsigned short f2bf(float x) {
    unsigned u = __float_as_uint(x);
    u += 0x7FFFu + ((u >> 16) & 1u);
    return (unsigned short)(u >> 16);
}
__device__ __forceinline__ float bf2f(unsigned short h) {
    return __uint_as_float(((unsigned)h) << 16);
}
__device__ __forceinline__ unsigned umin_(unsigned a, unsigned b) { return a < b ? a : b; }

// async global->LDS: 16B per lane, dest = uniform lds base + lane*16 (HW rule),
// src = per-lane global address. Identity copy when src = base + lane*16.
__device__ __forceinline__ void gload16(const void* g, void* l) {
    __builtin_amdgcn_global_load_lds(
        (const __attribute__((address_space(1))) unsigned int*)g,
        (__attribute__((address_space(3))) unsigned int*)l, 16, 0, 0);
}

union UV { uint4 v; bf16x8 h; unsigned short s[8]; };

// ws: pfmt byte[4 set][16384 pt][32] (4 MB) + d2part float[4 db][128 rb][8 seg][128] (2 MB).
// fragment map: elem = (g*32 + idx)*8 + j with k = g*8 + j (verified R2-R16)
// A k: [qh(3), ql(3), qh(2) | zh, 1,1,1, 1.0, 0,0,0]
// B k: [ph(3), ph(3), pl(2) | zl, -hp0,-hp1,-hp2, -32, 0,0,0]
// score s'' = q.p - hp - 32 (strictly negative) ; d^2 = 2*(hq - 32 - s'')
// Fold: negative floats => float-max == uint-min on bits; umin3 chains (R18).
//
// === DIAGNOSIS LEDGER ===
// R22 (hoisted staging regs @ 8 waves) = FAIL: 64-reg cap can't hold 4 uint4 prefetch
//   => main-loop scratch spill (WRITE 132 MB, FETCH 34 MB, chamfer 69us). ILP closed
//   at BOTH occupancy tiers (R19: 128-cap; R22: 64-cap). Conflict fix validated (6.29M->0).
// R23 (this): register-free staging via global_load_lds (async DMA, m97-proven w=16).
//   8 chunks x 8KB, LDS double-buffer; prefetch issued before pt loop; one barrier per
//   chunk (compiler vmcnt(0) drain). smem = max(16384, 16896) = 16.9KB -> 8 blocks/CU.
// R21: (256,8) occupancy step REAL (30->60%); quantum is power-of-2 (R20: no 5/6/7).
// R17: in-loop col-fold = +25us. R18: int fold neutral (kept). m119: MFMA ~32 cyc/SIMD.
//
// === FROZEN LEDGER (R2-R16) ===
// R11: ds_write/dest lane-consecutive-16B. R5/R7: no inline asm on MFMA results.
// R15/R16: unroll-2 / shuffle-epilogue = +14us. Keep unroll 1 + LDS-scratch epilogue.
// TIMING: dur_us includes fixed ~48us harness re-poison fill (268 MB). Addressable
//   budget = prep (~0.5) + chamfer + merge (~1.3).

// ---- prep: convert all points of both tensors/batches to the 32B LDS-image format ----
// set: 0,1 = src[b] ; 2,3 = tgt[b].  point p -> offset (p>>5)*1024 + (p&31)*16 (+512 for c1)
__global__ __launch_bounds__(256) void prep_kernel(
        const float* __restrict__ src, const float* __restrict__ tgt,
        unsigned char* __restrict__ pfmt, float* __restrict__ out)
{
    const int set = blockIdx.y;                   // 4 sets
    const int chunk = blockIdx.x;                 // 64 chunks x 256 pts
    const int tid = threadIdx.x;
    if (set == 0 && chunk == 0 && tid < 2) out[tid] = 0.0f;   // replaces memset node
    const float* base = (set < 2 ? src : tgt) + (size_t)(set & 1) * NPTS * 3;
    const int p = chunk * 256 + tid;
    const float x = base[p * 3 + 0], y = base[p * 3 + 1], z = base[p * 3 + 2];

    float hp = 0.5f * fmaf(z, z, fmaf(y, y, x * x));
    unsigned short xh = f2bf(x), yh = f2bf(y), zh = f2bf(z);
    unsigned short xl = f2bf(x - bf2f(xh)), yl = f2bf(y - bf2f(yh)), zl = f2bf(z - bf2f(zh));
    float rr = hp;
    unsigned short h0 = f2bf(rr); rr -= bf2f(h0);
    unsigned short h1 = f2bf(rr); rr -= bf2f(h1);
    unsigned short h2 = f2bf(rr);
    UV c0, c1;
    c0.s[0]=xh; c0.s[1]=yh; c0.s[2]=zh; c0.s[3]=xh; c0.s[4]=yh; c0.s[5]=zh; c0.s[6]=xl; c0.s[7]=yl;
    c1.s[0]=zl; c1.s[1]=(unsigned short)(h0^0x8000); c1.s[2]=(unsigned short)(h1^0x8000);
    c1.s[3]=(unsigned short)(h2^0x8000);
    c1.s[4]=0xC200;                     // bf16(-32) bias, pairs with A k12 = 1.0
    c1.s[5]=0; c1.s[6]=0; c1.s[7]=0;

    unsigned char* ob = pfmt + (size_t)set * NPTS * 32
                             + (size_t)(p >> 5) * 1024 + (size_t)(p & 31) * 16;
    *(uint4*)(ob)       = c0.v;
    *(uint4*)(ob + 512) = c1.v;
}

__global__ __launch_bounds__(256, 8) void chamfer_kernel(
        const float* __restrict__ src, const float* __restrict__ tgt,
        const unsigned char* __restrict__ pfmt, float* __restrict__ d2part)
{
    const int db = blockIdx.y, dir = db >> 1, b = db & 1;
    const int rowblock = blockIdx.x >> 3, seg = blockIdx.x & 7;   // 128 rowblocks x 8 segs
    const int tid = threadIdx.x, wave = tid >> 6, lane = tid & 63;
    const int g = lane >> 5, cc = lane & 31;
    const float* qp = (dir == 0 ? src : tgt) + (size_t)b * NPTS * 3;
    const int pset = (dir == 0 ? 2 + b : b);
    const unsigned char* ps = pfmt + (size_t)pset * NPTS * 32 + (size_t)seg * 2048 * 32;
    const unsigned short one = 0x3F80;

    // 2 x 8KB stage buffers; whole region aliased as 16.9KB epilogue scratch
    __shared__ alignas(16) unsigned char smem[16896];
    unsigned* scratch = (unsigned*)smem;

    // ---- A fragment + hq: ONE 32-row tile per wave (acc 16 regs) ----
    const int rt = rowblock * 4 + wave;
    bf16x8 afrag; float hq;
    {
        int r = rt * 32 + cc;
        float x = qp[r * 3 + 0], y = qp[r * 3 + 1], z = qp[r * 3 + 2];
        hq = 0.5f * fmaf(z, z, fmaf(y, y, x * x));
        unsigned short xh = f2bf(x), yh = f2bf(y), zh = f2bf(z);
        unsigned short xl = f2bf(x - bf2f(xh)), yl = f2bf(y - bf2f(yh)), zl = f2bf(z - bf2f(zh));
        UV f0, f1, rv;
        f0.s[0]=xh; f0.s[1]=yh; f0.s[2]=zh; f0.s[3]=xl; f0.s[4]=yl; f0.s[5]=zl; f0.s[6]=xh; f0.s[7]=yh;
        f1.s[0]=zh; f1.s[1]=one; f1.s[2]=one; f1.s[3]=one;
        f1.s[4]=one;                    // k12: pairs with B's bf16(-32) bias slot
        f1.s[5]=0; f1.s[6]=0; f1.s[7]=0;
        rv.v = g ? f1.v : f0.v;
        afrag = rv.h;
    }

    u32x16 m0 = 0xFF800000u;            // bits of -inf: umin identity here
    const f32x16 zc = 0.0f;

    // R23 staging: async DMA, zero registers. Per chunk (8KB): 2 calls/wave of 1KB.
    // dest = uniform(buf + wave*2048 [+1024]) + lane*16 ; src = same offsets in pfmt.
#define STAGE(CC, BUF) { \
    const unsigned char* gb = ps + (size_t)(CC) * 8192 + wave * 2048 + lane * 16; \
    unsigned char* lb = smem + (BUF) * 8192 + wave * 2048; \
    gload16(gb, lb); \
    gload16(gb + 1024, lb + 1024); }

    STAGE(0, 0)
    __syncthreads();                              // vmcnt(0) drain: chunk 0 resident
#pragma unroll 1
    for (int c = 0; c < 8; ++c) {                 // 8 chunks x 8 col-tiles
        if (c < 7) STAGE(c + 1, (c + 1) & 1)      // async prefetch into other buffer
        const unsigned short* bb = (const unsigned short*)(smem + (c & 1) * 8192);
#pragma unroll 1
        for (int pt = 0; pt < 4; ++pt) {          // 2 col-tiles per iter
            bf16x8 q0 = *(const bf16x8*)(bb + pt * 1024 + lane * 8);
            bf16x8 q1 = *(const bf16x8*)(bb + pt * 1024 + 512 + lane * 8);
            f32x16 t0 = __builtin_amdgcn_mfma_f32_32x32x16_bf16(afrag, q0, zc, 0, 0, 0);
            f32x16 t1 = __builtin_amdgcn_mfma_f32_32x32x16_bf16(afrag, q1, zc, 0, 0, 0);
#pragma unroll
            for (int j = 0; j < 16; j++)
                m0[j] = umin_(umin_(__float_as_uint(t0[j]), __float_as_uint(t1[j])), m0[j]);
        }
        __syncthreads();    // reads of buf[c&1] done + prefetch landed (vmcnt drain)
    }

    // ---- epilogue: acc bits -> padded LDS (per-wave private region) -> row reduce ----
    float* dst = d2part + (((size_t)(db * 128 + rowblock)) * 8 + seg) * 128;
    {
        unsigned* sc = scratch + wave * 1056;
#pragma unroll
        for (int j = 0; j < 16; j++) {
            int r0 = (j & 3) + 8 * (j >> 2) + 4 * g;
            sc[r0 * 33 + cc] = m0[j];
        }
        const unsigned* sr = sc + cc * 33 + g * 16;   // intra-wave dep: lgkmcnt orders it
        unsigned mx = 0xFF800000u;
#pragma unroll
        for (int k = 0; k < 16; k++) mx = umin_(mx, sr[k]);
        mx = umin_(mx, (unsigned)__shfl_xor((int)mx, 32, 64));
        if (lane < 32) {
            float sbi = __uint_as_float(mx);
            float d2 = 2.0f * (hq - 32.0f - sbi);
            float d = fminf(sqrtf(fmaxf(d2, 0.0f)), TH);
            dst[wave * 32 + lane] = d;
        }
    }
}

__global__ __launch_bounds__(256) void merge_kernel(const float* __restrict__ d2part,
                                                    float* __restrict__ out) {
    const int b = blockIdx.y;                     // batch
    const int slice = blockIdx.x;                 // 16 slices of 1024 rows
    const int tid = threadIdx.x;
    float s = 0.0f;
#pragma unroll
    for (int pass = 0; pass < 2; pass++) {        // dir 0 and dir 1
        const float* base = d2part + (size_t)(pass * 2 + b) * 128 * 8 * 128;
#pragma unroll
        for (int i = 0; i < 4; i++) {
            int r = slice * 1024 + i * 256 + tid;
            const float* p = base + (size_t)(r >> 7) * 1024 + (r & 127);
            float m = p[0];
#pragma unroll
            for (int sgi = 1; sgi < 8; sgi++) m = fminf(m, p[sgi * 128]);
            s += m;
        }
    }
#pragma unroll
    for (int off = 32; off > 0; off >>= 1) s += __shfl_down(s, off, 64);
    __shared__ float w[4];
    if ((tid & 63) == 0) w[tid >> 6] = s;
    __syncthreads();
    if (tid == 0) {
        float t = (w[0] + w[1]) + (w[2] + w[3]);
        atomicAdd(&out[b], t * (1.0f / (2.0f * NPTS)));  // (mean_fwd + mean_bwd) / 2
    }
}

extern "C" void kernel_launch(void* const* d_in, const int* in_sizes, int n_in,
                              void* d_out, int out_size, void* d_ws, size_t ws_size,
                              hipStream_t stream) {
    const float* src = (const float*)d_in[0];
    const float* tgt = (const float*)d_in[1];
    float* out = (float*)d_out;
    unsigned char* pfmt = (unsigned char*)d_ws;               // 4 MB
    float* d2part = (float*)(pfmt + (size_t)4 * 1024 * 1024); // 2 MB

    prep_kernel<<<dim3(64, 4), 256, 0, stream>>>(src, tgt, pfmt, out);
    chamfer_kernel<<<dim3(1024, 4), 256, 0, stream>>>(src, tgt, pfmt, d2part);
    merge_kernel<<<dim3(16, 2), 256, 0, stream>>>(d2part, out);
}